// Round 1
// baseline (875.060 us; speedup 1.0000x reference)
//
#include <hip/hip_runtime.h>
#include <math.h>

// Problem constants (B, S, D, MAXOBJ) = (512, 77, 2048, 4)
#define B_ 512
#define S_ 77
#define D_ 2048
#define EPS_ 1e-5f

typedef __attribute__((ext_vector_type(8))) short bf16x8;
typedef __attribute__((ext_vector_type(4))) float f32x4;

// fp32 -> bf16 bits, round-to-nearest-even
__device__ __forceinline__ unsigned short f2bf(float f) {
  union { float f; unsigned u; } x; x.f = f;
  return (unsigned short)((x.u + 0x7FFFu + ((x.u >> 16) & 1u)) >> 16);
}

// block=256 reduction of (sum, sumsq)
__device__ __forceinline__ void blockReduce2(float& a, float& b, float* sbuf) {
  #pragma unroll
  for (int off = 32; off > 0; off >>= 1) {
    a += __shfl_down(a, off, 64);
    b += __shfl_down(b, off, 64);
  }
  int lane = threadIdx.x & 63, wid = threadIdx.x >> 6;
  if (lane == 0) { sbuf[wid * 2] = a; sbuf[wid * 2 + 1] = b; }
  __syncthreads();
  if (threadIdx.x == 0) {
    float sa = 0.f, sb = 0.f;
    #pragma unroll
    for (int w = 0; w < 4; w++) { sa += sbuf[w * 2]; sb += sbuf[w * 2 + 1]; }
    sbuf[8] = sa; sbuf[9] = sb;
  }
  __syncthreads();
  a = sbuf[8]; b = sbuf[9];
}

// ---------------- bulk copy: inputs_embeds -> out (646 MB traffic, dominates) ----------------
__global__ __launch_bounds__(256)
void copy_kernel(const float4* __restrict__ src, float4* __restrict__ dst, long n4) {
  long i = (long)blockIdx.x * blockDim.x + threadIdx.x;
  long stride = (long)gridDim.x * blockDim.x;
  for (; i < n4; i += stride) dst[i] = src[i];
}

// ---------------- prep: idx, tok, mean_obj, LN1 over 4096, write bf16 X ----------------
__global__ __launch_bounds__(256)
void prep_kernel(const float* __restrict__ x_embed, const float* __restrict__ obj,
                 const int* __restrict__ mask, const int* __restrict__ nobj,
                 const float* __restrict__ g, const float* __restrict__ bb,
                 int* __restrict__ idx_out, float* __restrict__ tok_out,
                 unsigned short* __restrict__ xln_out) {
  __shared__ int s_idx;
  __shared__ float sbuf[10];
  const int b = blockIdx.x, t = threadIdx.x;
  if (t == 0) s_idx = 0;
  __syncthreads();
  for (int j = t; j < S_; j += 256)
    if (mask[b * S_ + j] != 0) atomicMax(&s_idx, j);
  __syncthreads();
  const int idx = s_idx;
  if (t == 0) idx_out[b] = idx;

  const float4* tokrow = (const float4*)(x_embed + ((long)b * S_ + idx) * D_);
  float4 t0 = tokrow[t * 2];
  float4 t1 = tokrow[t * 2 + 1];
  ((float4*)(tok_out + (long)b * D_))[t * 2] = t0;
  ((float4*)(tok_out + (long)b * D_))[t * 2 + 1] = t1;

  const int n = nobj[b];
  const float inv_n = 1.0f / (float)n;
  float4 s0 = make_float4(0.f, 0.f, 0.f, 0.f), s1 = s0;
  for (int o = 0; o < n; o++) {
    const float4* orow = (const float4*)(obj + ((long)b * 4 + o) * D_);
    float4 q0 = orow[t * 2], q1 = orow[t * 2 + 1];
    s0.x += q0.x; s0.y += q0.y; s0.z += q0.z; s0.w += q0.w;
    s1.x += q1.x; s1.y += q1.y; s1.z += q1.z; s1.w += q1.w;
  }
  float vals[16] = { t0.x, t0.y, t0.z, t0.w, t1.x, t1.y, t1.z, t1.w,
                     s0.x * inv_n, s0.y * inv_n, s0.z * inv_n, s0.w * inv_n,
                     s1.x * inv_n, s1.y * inv_n, s1.z * inv_n, s1.w * inv_n };
  float sum = 0.f, sq = 0.f;
  #pragma unroll
  for (int i = 0; i < 16; i++) { sum += vals[i]; sq += vals[i] * vals[i]; }
  blockReduce2(sum, sq, sbuf);
  const float mu = sum * (1.f / 4096.f);
  const float rstd = rsqrtf(sq * (1.f / 4096.f) - mu * mu + EPS_);
  #pragma unroll
  for (int i = 0; i < 16; i++) {
    int d = (i < 8) ? (t * 8 + i) : (D_ + t * 8 + (i - 8));
    float v = (vals[i] - mu) * rstd * g[d] + bb[d];
    xln_out[(long)b * (2 * D_) + d] = f2bf(v);
  }
}

// ---------------- bf16 MFMA GEMM: out = epi(A[MxK](bf16) @ W[KxN](f32->bf16) + bias) ----------------
template<int GELU, int HAS_RES, int OUT_BF16>
__global__ __launch_bounds__(256)
void gemm_kernel(const unsigned short* __restrict__ A, const float* __restrict__ W,
                 const float* __restrict__ bias, const float* __restrict__ res,
                 void* __restrict__ outp, int M, int N, int K) {
  constexpr int LDA = 72, LDB = 72;  // +8 bf16 pad breaks power-of-2 bank strides
  __shared__ __align__(16) unsigned short As[64 * LDA];
  __shared__ __align__(16) unsigned short Bs[64 * LDB];
  const int tid = threadIdx.x;
  const int m0 = blockIdx.y * 64;
  const int n0 = blockIdx.x * 64;
  const int lane = tid & 63;
  const int wave = tid >> 6;
  const int l16 = lane & 15;
  const int quad = lane >> 4;
  const int wm = (wave & 1) * 32;
  const int wn = (wave >> 1) * 32;

  f32x4 acc[2][2];
  #pragma unroll
  for (int i = 0; i < 2; i++)
    #pragma unroll
    for (int j = 0; j < 2; j++) acc[i][j] = (f32x4){0.f, 0.f, 0.f, 0.f};

  const int arow = tid >> 3;        // 0..31
  const int acol = (tid & 7) * 8;   // 0..56 (bf16 elems)
  const int bk4 = (tid >> 4) * 4;   // k base 0..60
  const int bn4 = (tid & 15) * 4;   // n base 0..60

  for (int k0 = 0; k0 < K; k0 += 64) {
    // stage A tile (64x64 bf16), 16B per access
    *(uint4*)&As[arow * LDA + acol] =
        *(const uint4*)&A[(long)(m0 + arow) * K + k0 + acol];
    *(uint4*)&As[(arow + 32) * LDA + acol] =
        *(const uint4*)&A[(long)(m0 + arow + 32) * K + k0 + acol];
    // stage B tile: read 4x4 f32 micro-tile, convert->bf16, transpose into Bs[n][k]
    float4 w0 = *(const float4*)&W[(long)(k0 + bk4 + 0) * N + n0 + bn4];
    float4 w1 = *(const float4*)&W[(long)(k0 + bk4 + 1) * N + n0 + bn4];
    float4 w2 = *(const float4*)&W[(long)(k0 + bk4 + 2) * N + n0 + bn4];
    float4 w3 = *(const float4*)&W[(long)(k0 + bk4 + 3) * N + n0 + bn4];
    {
      unsigned long long p;
      p = (unsigned long long)f2bf(w0.x) | ((unsigned long long)f2bf(w1.x) << 16) |
          ((unsigned long long)f2bf(w2.x) << 32) | ((unsigned long long)f2bf(w3.x) << 48);
      *(unsigned long long*)&Bs[(bn4 + 0) * LDB + bk4] = p;
      p = (unsigned long long)f2bf(w0.y) | ((unsigned long long)f2bf(w1.y) << 16) |
          ((unsigned long long)f2bf(w2.y) << 32) | ((unsigned long long)f2bf(w3.y) << 48);
      *(unsigned long long*)&Bs[(bn4 + 1) * LDB + bk4] = p;
      p = (unsigned long long)f2bf(w0.z) | ((unsigned long long)f2bf(w1.z) << 16) |
          ((unsigned long long)f2bf(w2.z) << 32) | ((unsigned long long)f2bf(w3.z) << 48);
      *(unsigned long long*)&Bs[(bn4 + 2) * LDB + bk4] = p;
      p = (unsigned long long)f2bf(w0.w) | ((unsigned long long)f2bf(w1.w) << 16) |
          ((unsigned long long)f2bf(w2.w) << 32) | ((unsigned long long)f2bf(w3.w) << 48);
      *(unsigned long long*)&Bs[(bn4 + 3) * LDB + bk4] = p;
    }
    __syncthreads();
    #pragma unroll
    for (int kk = 0; kk < 64; kk += 32) {
      bf16x8 a[2], bf[2];
      a[0]  = *(const bf16x8*)&As[(wm + l16) * LDA + kk + quad * 8];
      a[1]  = *(const bf16x8*)&As[(wm + 16 + l16) * LDA + kk + quad * 8];
      bf[0] = *(const bf16x8*)&Bs[(wn + l16) * LDB + kk + quad * 8];
      bf[1] = *(const bf16x8*)&Bs[(wn + 16 + l16) * LDB + kk + quad * 8];
      #pragma unroll
      for (int mt = 0; mt < 2; mt++)
        #pragma unroll
        for (int nt = 0; nt < 2; nt++)
          acc[mt][nt] = __builtin_amdgcn_mfma_f32_16x16x32_bf16(a[mt], bf[nt], acc[mt][nt], 0, 0, 0);
    }
    __syncthreads();
  }
  // epilogue: C/D layout col=lane&15, row=quad*4+r
  #pragma unroll
  for (int mt = 0; mt < 2; mt++) {
    #pragma unroll
    for (int nt = 0; nt < 2; nt++) {
      const int col = n0 + wn + nt * 16 + l16;
      const float bc = bias[col];
      #pragma unroll
      for (int r = 0; r < 4; r++) {
        const int row = m0 + wm + mt * 16 + quad * 4 + r;
        float v = acc[mt][nt][r] + bc;
        if constexpr (HAS_RES) v += res[(long)row * N + col];
        if constexpr (GELU) v = 0.5f * v * (1.f + erff(v * 0.70710678118654752f));
        if constexpr (OUT_BF16)
          ((unsigned short*)outp)[(long)row * N + col] = f2bf(v);
        else
          ((float*)outp)[(long)row * N + col] = v;
      }
    }
  }
}

// ---------------- LN over 2048, bf16 out (mlp2 input) ----------------
__global__ __launch_bounds__(256)
void ln_bf16_kernel(const float* __restrict__ in, const float* __restrict__ g,
                    const float* __restrict__ bb, unsigned short* __restrict__ out) {
  __shared__ float sbuf[10];
  const int b = blockIdx.x, t = threadIdx.x;
  const float4* row = (const float4*)(in + (long)b * D_);
  float4 v0 = row[t * 2], v1 = row[t * 2 + 1];
  float o[8] = { v0.x, v0.y, v0.z, v0.w, v1.x, v1.y, v1.z, v1.w };
  float sum = 0.f, sq = 0.f;
  #pragma unroll
  for (int i = 0; i < 8; i++) { sum += o[i]; sq += o[i] * o[i]; }
  blockReduce2(sum, sq, sbuf);
  const float mu = sum * (1.f / 2048.f);
  const float rstd = rsqrtf(sq * (1.f / 2048.f) - mu * mu + EPS_);
  const int d0 = t * 8;
  #pragma unroll
  for (int i = 0; i < 8; i++)
    out[(long)b * D_ + d0 + i] = f2bf((o[i] - mu) * rstd * g[d0 + i] + bb[d0 + i]);
}

// ---------------- final LN + scatter into out[b, idx[b], :] ----------------
__global__ __launch_bounds__(256)
void final_kernel(const float* __restrict__ in, const float* __restrict__ g,
                  const float* __restrict__ bb, const int* __restrict__ idxbuf,
                  float* __restrict__ out) {
  __shared__ float sbuf[10];
  const int b = blockIdx.x, t = threadIdx.x;
  const float4* row = (const float4*)(in + (long)b * D_);
  float4 v0 = row[t * 2], v1 = row[t * 2 + 1];
  float o[8] = { v0.x, v0.y, v0.z, v0.w, v1.x, v1.y, v1.z, v1.w };
  float sum = 0.f, sq = 0.f;
  #pragma unroll
  for (int i = 0; i < 8; i++) { sum += o[i]; sq += o[i] * o[i]; }
  blockReduce2(sum, sq, sbuf);
  const float mu = sum * (1.f / 2048.f);
  const float rstd = rsqrtf(sq * (1.f / 2048.f) - mu * mu + EPS_);
  float* orow = out + ((long)b * S_ + idxbuf[b]) * D_;
  const int d0 = t * 8;
  #pragma unroll
  for (int i = 0; i < 8; i++) o[i] = (o[i] - mu) * rstd * g[d0 + i] + bb[d0 + i];
  ((float4*)orow)[t * 2]     = make_float4(o[0], o[1], o[2], o[3]);
  ((float4*)orow)[t * 2 + 1] = make_float4(o[4], o[5], o[6], o[7]);
}

extern "C" void kernel_launch(void* const* d_in, const int* in_sizes, int n_in,
                              void* d_out, int out_size, void* d_ws, size_t ws_size,
                              hipStream_t stream) {
  const float* inputs_embeds = (const float*)d_in[0];
  const float* object_embeds = (const float*)d_in[1];
  const float* mlp1_ln_g = (const float*)d_in[2];
  const float* mlp1_ln_b = (const float*)d_in[3];
  const float* mlp1_w1   = (const float*)d_in[4];
  const float* mlp1_b1   = (const float*)d_in[5];
  const float* mlp1_w2   = (const float*)d_in[6];
  const float* mlp1_b2   = (const float*)d_in[7];
  const float* mlp2_ln_g = (const float*)d_in[8];
  const float* mlp2_ln_b = (const float*)d_in[9];
  const float* mlp2_w1   = (const float*)d_in[10];
  const float* mlp2_b1   = (const float*)d_in[11];
  const float* mlp2_w2   = (const float*)d_in[12];
  const float* mlp2_b2   = (const float*)d_in[13];
  const float* ln_g      = (const float*)d_in[14];
  const float* ln_b      = (const float*)d_in[15];
  const int* mask        = (const int*)d_in[16];
  const int* nobj        = (const int*)d_in[17];

  char* ws = (char*)d_ws;
  int*            idxbuf = (int*)ws;                                   // 512 ints
  float*          tok    = (float*)(ws + 4096);                        // 512x2048 f32
  unsigned short* xln    = (unsigned short*)(ws + 4096 + 4194304);     // 512x4096 bf16
  unsigned short* h1     = (unsigned short*)(ws + 4096 + 8388608);     // 512x2048 bf16
  float*          h2     = (float*)(ws + 4096 + 10485760);             // 512x2048 f32
  unsigned short* x2ln   = (unsigned short*)(ws + 4096 + 14680064);    // 512x2048 bf16
  unsigned short* h3     = (unsigned short*)(ws + 4096 + 16777216);    // 512x2048 bf16
  float*          h4     = (float*)(ws + 4096 + 18874368);             // 512x2048 f32

  const long n4 = (long)B_ * S_ * D_ / 4;
  copy_kernel<<<4096, 256, 0, stream>>>((const float4*)inputs_embeds, (float4*)d_out, n4);

  prep_kernel<<<B_, 256, 0, stream>>>(inputs_embeds, object_embeds, mask, nobj,
                                      mlp1_ln_g, mlp1_ln_b, idxbuf, tok, xln);

  dim3 gg(2048 / 64, B_ / 64);  // (N/64, M/64) = (32, 8)
  gemm_kernel<1, 0, 1><<<gg, 256, 0, stream>>>(xln,  mlp1_w1, mlp1_b1, nullptr, h1, B_, D_, 2 * D_);
  gemm_kernel<0, 1, 0><<<gg, 256, 0, stream>>>(h1,   mlp1_w2, mlp1_b2, tok,     h2, B_, D_, D_);
  ln_bf16_kernel<<<B_, 256, 0, stream>>>(h2, mlp2_ln_g, mlp2_ln_b, x2ln);
  gemm_kernel<1, 0, 1><<<gg, 256, 0, stream>>>(x2ln, mlp2_w1, mlp2_b1, nullptr, h3, B_, D_, D_);
  gemm_kernel<0, 1, 0><<<gg, 256, 0, stream>>>(h3,   mlp2_w2, mlp2_b2, h2,      h4, B_, D_, D_);
  final_kernel<<<B_, 256, 0, stream>>>(h4, ln_g, ln_b, idxbuf, (float*)d_out);
}